// Round 2
// baseline (228.919 us; speedup 1.0000x reference)
//
#include <hip/hip_runtime.h>
#include <hip/hip_cooperative_groups.h>
#include <cstdint>

namespace cg = cooperative_groups;

#define NNODES 10000
#define FDIM 128
#define MAXDEG 192
#define SLOTS 48                           // per-stripe slots (4*48 = 192)

typedef _Float16 h2v  __attribute__((ext_vector_type(2)));
typedef _Float16 f16x8 __attribute__((ext_vector_type(8)));
typedef float    f32x4 __attribute__((ext_vector_type(4)));

// Module-owned scratch (BSS, zero at load) — no d_ws dependence.
// g_cnt invariant: zero at entry to every kernel_launch (BSS on first call;
// layer<1> phase re-zeroes its groups' counters after last use every call).
// Row NNODES of g_xh/g_h1h is a SENTINEL ZERO row (never written): gather
// tails are padded to multiples of 4 edges by pointing at it.
__device__ __align__(16)  int      g_cnt[NNODES * 4];     // striped degree counters
__device__                int      g_bucket[NNODES * MAXDEG]; // stripe sub-lists
__device__ __align__(256) unsigned g_xh [(NNODES + 1) * FDIM / 2]; // x  fp16x2
__device__ __align__(256) unsigned g_h1h[(NNODES + 1) * FDIM / 2]; // h1 fp16x2
__device__ __align__(16)  unsigned g_wf[2 * 8192];        // W1/W2 pre-packed B-frags

__device__ inline h2v as_h2(unsigned u) { return __builtin_bit_cast(h2v, u); }
__device__ inline unsigned as_u(h2v v) { return __builtin_bit_cast(unsigned, v); }
__device__ inline unsigned pack_f16x2(float a, float b) {
  h2v v; v[0] = (_Float16)a; v[1] = (_Float16)b;
  return as_u(v);
}
__device__ inline void vadd4(uint4& a, const uint4& b) {   // 4x v_pk_add_f16
  a.x = as_u(as_h2(a.x) + as_h2(b.x));
  a.y = as_u(as_h2(a.y) + as_h2(b.y));
  a.z = as_u(as_h2(a.z) + as_h2(b.z));
  a.w = as_u(as_h2(a.w) + as_h2(b.w));
}

// ---------------- fused GIN layer phase (runs inside cooperative kernel) ----
// 16 nodes/group, 8-wave cooperative. Wave w gathers nodes node0+2w, +1 with
// dwordx4 rows: lane (quad q, m16) reads 16 B of row edge[4s+q] -> one
// wave-load consumes 4 edges (1 KB). Tails padded with sentinel zero row.
// Quad partials folded by xor-16/xor-32 butterfly; quad-0 lanes write A row.
// Phase 2: wave w computes feature-tile n = w with B-fragments held in
// REGISTERS (loaded once per layer from pre-packed g_wf; no LDS W staging):
// 4 kchunks of v_mfma_f32_16x16x32_f16 (A/B frag [idx=lane&15][k=(lane>>4)*8+j];
// D col=lane&15(+16n), row=(lane>>4)*4+reg).
// MODE 0: relu -> g_h1h (packed fp16x2). MODE 1: log_softmax -> out_g (fp32)
//         + re-zero this group's stripe counters.
template <int MODE>
__device__ __forceinline__ void layer_phase(
    const float* __restrict__ bvec, float* __restrict__ out_g,
    unsigned* __restrict__ al,      // 16*68 dwords A tile (+4 pad/row)
    unsigned* __restrict__ cfu) {   // 16*132 dwords epilogue scratch
  const unsigned* __restrict__ xh = (MODE == 0) ? g_xh : g_h1h;

  const int tid = threadIdx.x;
  const int wave = tid >> 6, lane = tid & 63;
  const int quad = lane >> 4, m16 = lane & 15;

  // B-fragments in registers: constant per wave for the whole layer.
  uint4 bf[4];
  {
    const unsigned* wfp = g_wf + (MODE ? 8192 : 0);
#pragma unroll
    for (int kc = 0; kc < 4; ++kc)
      bf[kc] = *(const uint4*)(wfp + ((wave * 4 + kc) * 64 + lane) * 4);
  }
  const float bb = bvec[wave * 16 + m16];

  for (int grp = blockIdx.x; grp < 625; grp += gridDim.x) {
    const int node0 = grp * 16;
    const int myn0 = node0 + wave * 2;

    // ---- phase 1 prologue: self rows + stripe counters for my 2 nodes ----
    uint4 self4[2];
    int o1[2], o2[2], o3[2], dgg[2];
#pragma unroll
    for (int i = 0; i < 2; ++i) {
      self4[i] = *(const uint4*)(xh + (size_t)(myn0 + i) * 64 + (m16 << 2));
      int4 c = *(const int4*)(g_cnt + (myn0 + i) * 4);
      int a = (c.x > SLOTS) ? SLOTS : c.x;
      int bq = (c.y > SLOTS) ? SLOTS : c.y;
      int cq = (c.z > SLOTS) ? SLOTS : c.z;
      int dq = (c.w > SLOTS) ? SLOTS : c.w;
      o1[i] = a; o2[i] = a + bq; o3[i] = a + bq + cq; dgg[i] = a + bq + cq + dq;
    }

    for (int i = 0; i < 2; ++i) {
      h2v a0 = as_h2(0u), a1 = as_h2(0u), a2 = as_h2(0u), a3 = as_h2(0u);
      const int deg = dgg[i];
      const int* nb = g_bucket + (size_t)(myn0 + i) * MAXDEG;
      for (int p = 0; p < deg; p += 64) {
        int n = deg - p; if (n > 64) n = 64;
        int myedge = NNODES;               // sentinel zero row for padding
        if (lane < n) {                    // stripe-select index fetch
          int g = p + lane;
          int base = 0;
          if (g >= o1[i]) base = o1[i];
          if (g >= o2[i]) base = o2[i];
          if (g >= o3[i]) base = o3[i];
          int st = (g >= o1[i]) + (g >= o2[i]) + (g >= o3[i]);
          myedge = nb[st * SLOTS + (g - base)];
        }
        const int nst = (n + 3) >> 2;      // 4-edge steps (sentinel-padded)
        int s = 0;
        for (; s + 8 <= nst; s += 8) {     // 8 dwordx4 (=32 edges) in flight
          uint4 t[8];
#pragma unroll
          for (int k = 0; k < 8; ++k) {
            int e = __builtin_amdgcn_ds_bpermute((((s + k) << 2) | quad) << 2, myedge);
            t[k] = *(const uint4*)(xh + (unsigned)((e << 6) | (m16 << 2)));
          }
#pragma unroll
          for (int st2 = 1; st2 < 8; st2 <<= 1)
#pragma unroll
            for (int k = 0; k < 8; k += 2 * st2) vadd4(t[k], t[k + st2]);
          a0 += as_h2(t[0].x); a1 += as_h2(t[0].y);
          a2 += as_h2(t[0].z); a3 += as_h2(t[0].w);
        }
        if (s + 4 <= nst) {                // 4-step batch (16 edges)
          uint4 t[4];
#pragma unroll
          for (int k = 0; k < 4; ++k) {
            int e = __builtin_amdgcn_ds_bpermute((((s + k) << 2) | quad) << 2, myedge);
            t[k] = *(const uint4*)(xh + (unsigned)((e << 6) | (m16 << 2)));
          }
          vadd4(t[0], t[1]); vadd4(t[2], t[3]); vadd4(t[0], t[2]);
          a0 += as_h2(t[0].x); a1 += as_h2(t[0].y);
          a2 += as_h2(t[0].z); a3 += as_h2(t[0].w);
          s += 4;
        }
        for (; s < nst; ++s) {             // <=3 single steps
          int e = __builtin_amdgcn_ds_bpermute(((s << 2) | quad) << 2, myedge);
          uint4 t = *(const uint4*)(xh + (unsigned)((e << 6) | (m16 << 2)));
          a0 += as_h2(t.x); a1 += as_h2(t.y); a2 += as_h2(t.z); a3 += as_h2(t.w);
        }
      }
      // fold the 4 quad partials (xor-16 then xor-32 butterfly)
      int r;
      r = __shfl_xor((int)as_u(a0), 16, 64); a0 += as_h2((unsigned)r);
      r = __shfl_xor((int)as_u(a0), 32, 64); a0 += as_h2((unsigned)r);
      r = __shfl_xor((int)as_u(a1), 16, 64); a1 += as_h2((unsigned)r);
      r = __shfl_xor((int)as_u(a1), 32, 64); a1 += as_h2((unsigned)r);
      r = __shfl_xor((int)as_u(a2), 16, 64); a2 += as_h2((unsigned)r);
      r = __shfl_xor((int)as_u(a2), 32, 64); a2 += as_h2((unsigned)r);
      r = __shfl_xor((int)as_u(a3), 16, 64); a3 += as_h2((unsigned)r);
      r = __shfl_xor((int)as_u(a3), 32, 64); a3 += as_h2((unsigned)r);
      // (1+eps)*x self term, added once after the fold
      a0 += as_h2(self4[i].x); a1 += as_h2(self4[i].y);
      a2 += as_h2(self4[i].z); a3 += as_h2(self4[i].w);
      if (quad == 0)
        *(uint4*)(al + (wave * 2 + i) * 68 + (m16 << 2)) =
            make_uint4(as_u(a0), as_u(a1), as_u(a2), as_u(a3));
    }
    __syncthreads();                       // A tile visible to all waves

    // ---- phase 2: MFMA, ntile n = wave, B from registers ----
    uint4 af[4];
#pragma unroll
    for (int kc = 0; kc < 4; ++kc)
      af[kc] = *(const uint4*)(al + m16 * 68 + kc * 16 + quad * 4);

    const int n = wave;
    f32x4 acc = {0.f, 0.f, 0.f, 0.f};
#pragma unroll
    for (int kc = 0; kc < 4; ++kc)
      acc = __builtin_amdgcn_mfma_f32_16x16x32_f16(
              __builtin_bit_cast(f16x8, af[kc]),
              __builtin_bit_cast(f16x8, bf[kc]), acc, 0, 0, 0);

    // ---- epilogue (cfu scratch; al reads all complete before cfu sync) ----
    if (MODE == 0) {
      // relu + fp16 pack: rows padded to 136 halves for bank spread
      _Float16* ch = (_Float16*)cfu;
      const int f = n * 16 + m16;
#pragma unroll
      for (int reg = 0; reg < 4; ++reg)
        ch[(quad * 4 + reg) * 136 + f] = (_Float16)fmaxf(acc[reg] + bb, 0.f);
      __syncthreads();
      const int row = tid >> 5, c2 = (tid & 31) * 2;
      uint2 v = *(const uint2*)(cfu + row * 68 + c2);
      *(uint2*)(&g_h1h[(size_t)(node0 + row) * 64 + c2]) = v;
    } else {
      // log_softmax: vals to LDS fp32 (rows padded to 132 floats)
      float* cf = (float*)cfu;
      const int f = n * 16 + m16;
#pragma unroll
      for (int reg = 0; reg < 4; ++reg)
        cf[(quad * 4 + reg) * 132 + f] = acc[reg] + bb;
      __syncthreads();
      const int row = tid >> 5, li = tid & 31;   // 32 threads per row
      const float* base = cf + row * 132 + li * 4;
      float4 a4 = *(const float4*)(base);
      float mx = fmaxf(fmaxf(a4.x, a4.y), fmaxf(a4.z, a4.w));
#pragma unroll
      for (int off = 16; off >= 1; off >>= 1)
        mx = fmaxf(mx, __shfl_xor(mx, off, 64));   // within 32-lane half-wave
      float s = (__expf(a4.x - mx) + __expf(a4.y - mx))
              + (__expf(a4.z - mx) + __expf(a4.w - mx));
#pragma unroll
      for (int off = 16; off >= 1; off >>= 1)
        s += __shfl_xor(s, off, 64);
      const float ls = mx + __logf(s);
      float* orow = out_g + (size_t)(node0 + row) * FDIM + li * 4;
      *(float4*)(orow) = make_float4(a4.x - ls, a4.y - ls, a4.z - ls, a4.w - ls);
      // restore counter invariant: this group's 16 nodes x 4 stripes
      if (tid < 64) g_cnt[node0 * 4 + tid] = 0;
    }
  }
}

// ---------------- single cooperative kernel: prep -> L1 -> L2 -------------
// Grid <= 2 blocks/CU co-resident (LDS 12.8 KB, VGPR capped 128 via
// __launch_bounds__(512,4)); grid.sync() carries the device-scope fence for
// cross-XCD visibility of g_xh/g_bucket (phase 0 -> L1) and g_h1h (L1 -> L2).
__global__ __launch_bounds__(512, 4) void fused_gin_kernel(
    const float* __restrict__ x, const int* __restrict__ ei,
    const float* __restrict__ w1, const float* __restrict__ b1,
    const float* __restrict__ w2, const float* __restrict__ b2,
    float* __restrict__ out, int E_) {
  __shared__ __align__(16) unsigned s_al[16 * 68];    // 4.35 KB A tile
  __shared__ __align__(16) unsigned s_cf[16 * 132];   // 8.45 KB epilogue scratch

  const int tid = threadIdx.x;
  const int gsz = gridDim.x * 512;
  const int gtid = blockIdx.x * 512 + tid;

  // ---- phase 0a: striped-atomic bucket fill ----
  for (int e = gtid; e < E_; e += gsz) {
    int d = ei[E_ + e];                    // dst
    int s = ei[e];                         // src
    int st = e & 3;
    int p = atomicAdd(&g_cnt[d * 4 + st], 1);
    if (p < SLOTS) g_bucket[d * MAXDEG + st * SLOTS + p] = s;
  }
  // ---- phase 0b: cast x -> fp16x2 (float4 -> uint2) ----
  for (int i = gtid; i < NNODES * 32; i += gsz) {
    float4 v = *(const float4*)(x + 4 * (size_t)i);
    uint2 o; o.x = pack_f16x2(v.x, v.y); o.y = pack_f16x2(v.z, v.w);
    *(uint2*)(g_xh + 2 * (size_t)i) = o;
  }
  // ---- phase 0c: pack W1/W2 into MFMA B-fragment dword layout ----
  for (int idx = gtid; idx < 4096; idx += gsz) {
    const float* w = (idx >= 2048) ? w2 : w1;
    int s = idx & 2047;
    int sl = s & 63, nk = s >> 6;
    int n = nk >> 2, kc = nk & 3;
    int kbase = kc * 32 + (sl >> 4) * 8;
    int f = n * 16 + (sl & 15);
    unsigned d0 = pack_f16x2(w[(size_t)(kbase + 0) * FDIM + f],
                             w[(size_t)(kbase + 1) * FDIM + f]);
    unsigned d1 = pack_f16x2(w[(size_t)(kbase + 2) * FDIM + f],
                             w[(size_t)(kbase + 3) * FDIM + f]);
    unsigned d2 = pack_f16x2(w[(size_t)(kbase + 4) * FDIM + f],
                             w[(size_t)(kbase + 5) * FDIM + f]);
    unsigned d3 = pack_f16x2(w[(size_t)(kbase + 6) * FDIM + f],
                             w[(size_t)(kbase + 7) * FDIM + f]);
    *(uint4*)(g_wf + (idx >> 11) * 8192 + 4 * s) = make_uint4(d0, d1, d2, d3);
  }

  cg::this_grid().sync();                  // buckets + xh + wf visible grid-wide
  layer_phase<0>(b1, nullptr, s_al, s_cf);
  cg::this_grid().sync();                  // h1 visible grid-wide
  layer_phase<1>(b2, out, s_al, s_cf);
}

extern "C" void kernel_launch(void* const* d_in, const int* in_sizes, int n_in,
                              void* d_out, int out_size, void* d_ws, size_t ws_size,
                              hipStream_t stream) {
  const float* x  = (const float*)d_in[0];
  const int*   ei = (const int*)d_in[1];     // int64 in reference -> int32 here
  const float* w1 = (const float*)d_in[2];
  const float* b1 = (const float*)d_in[3];
  const float* w2 = (const float*)d_in[4];
  const float* b2 = (const float*)d_in[5];
  float* out = (float*)d_out;
  int E_ = in_sizes[1] / 2;

  // Grid sized once for guaranteed co-residency (cooperative requirement).
  static int nblk = 0;
  if (nblk == 0) {
    int per = 0;
    if (hipOccupancyMaxActiveBlocksPerMultiprocessor(&per, fused_gin_kernel,
                                                     512, 0) != hipSuccess ||
        per < 1)
      per = 1;
    long cap = (long)per * 256;
    nblk = (int)(cap < 625 ? cap : 625);
  }

  void* args[] = {(void*)&x, (void*)&ei, (void*)&w1, (void*)&b1,
                  (void*)&w2, (void*)&b2, (void*)&out, (void*)&E_};
  hipLaunchCooperativeKernel((const void*)fused_gin_kernel, dim3(nblk),
                             dim3(512), args, 0, stream);
}

// Round 3
// 127.923 us; speedup vs baseline: 1.7895x; 1.7895x over previous
//
#include <hip/hip_runtime.h>
#include <cstdint>

#define NNODES 10000
#define FDIM 128
#define MAXDEG 192
#define SLOTS 48                           // per-stripe slots (4*48 = 192)

typedef _Float16 h2v  __attribute__((ext_vector_type(2)));
typedef _Float16 f16x8 __attribute__((ext_vector_type(8)));
typedef float    f32x4 __attribute__((ext_vector_type(4)));

// Module-owned scratch (BSS, zero at load) — no d_ws dependence.
// g_cnt invariant: zero at entry to every kernel_launch (BSS on first call;
// gin_layer<1> re-zeroes its blocks' counters after last use every call).
// Row NNODES of g_xh/g_h1h is a SENTINEL ZERO row (never written): gather
// tails are padded to multiples of 4 edges by pointing at it.
__device__ __align__(16)  int      g_cnt[NNODES * 4];     // striped degree counters
__device__                int      g_bucket[NNODES * MAXDEG]; // stripe sub-lists
__device__ __align__(256) unsigned g_xh [(NNODES + 1) * FDIM / 2]; // x  fp16x2
__device__ __align__(256) unsigned g_h1h[(NNODES + 1) * FDIM / 2]; // h1 fp16x2
__device__ __align__(16)  unsigned g_wf[2 * 8192];        // W1/W2 pre-packed B-frags

__device__ inline h2v as_h2(unsigned u) { return __builtin_bit_cast(h2v, u); }
__device__ inline unsigned as_u(h2v v) { return __builtin_bit_cast(unsigned, v); }
__device__ inline unsigned pack_f16x2(float a, float b) {
  h2v v; v[0] = (_Float16)a; v[1] = (_Float16)b;
  return as_u(v);
}
__device__ inline void vadd4(uint4& a, const uint4& b) {   // 4x v_pk_add_f16
  a.x = as_u(as_h2(a.x) + as_h2(b.x));
  a.y = as_u(as_h2(a.y) + as_h2(b.y));
  a.z = as_u(as_h2(a.z) + as_h2(b.z));
  a.w = as_u(as_h2(a.w) + as_h2(b.w));
}

// ---------------- prep: bucket fill + x cast (float4) + W pre-pack --------
__global__ __launch_bounds__(256) void prep_kernel(
    const float* __restrict__ x, const int* __restrict__ ei,
    const float* __restrict__ w1, const float* __restrict__ w2,
    int E_, int EBLK, int CBLK) {
  const int bid = blockIdx.x;
  if (bid < EBLK) {
    int e = bid * 256 + threadIdx.x;
    if (e < E_) {
      int d = ei[E_ + e];                  // dst
      int s = ei[e];                       // src
      int st = e & 3;
      int p = atomicAdd(&g_cnt[d * 4 + st], 1);
      if (p < SLOTS) g_bucket[d * MAXDEG + st * SLOTS + p] = s;
    }
  } else if (bid < EBLK + CBLK) {
    int i = (bid - EBLK) * 256 + threadIdx.x;
    if (i < NNODES * 32) {                 // float4 -> fp16x2 pair (16B->8B)
      float4 v = *(const float4*)(x + 4 * (size_t)i);
      uint2 o; o.x = pack_f16x2(v.x, v.y); o.y = pack_f16x2(v.z, v.w);
      *(uint2*)(g_xh + 2 * (size_t)i) = o;
    }
  } else {
    // pack W1/W2 into the exact MFMA B-fragment dword layout once.
    // entry s -> (nk = s>>6, sl = s&63), n = nk>>2, kc = nk&3,
    // kbase = kc*32 + (sl>>4)*8, f = n*16 + (sl&15).
    int idx = (bid - EBLK - CBLK) * 256 + threadIdx.x;  // 0..4095
    const float* w = (idx >= 2048) ? w2 : w1;
    int s = idx & 2047;
    int sl = s & 63, nk = s >> 6;
    int n = nk >> 2, kc = nk & 3;
    int kbase = kc * 32 + (sl >> 4) * 8;
    int f = n * 16 + (sl & 15);
    unsigned d0 = pack_f16x2(w[(size_t)(kbase + 0) * FDIM + f],
                             w[(size_t)(kbase + 1) * FDIM + f]);
    unsigned d1 = pack_f16x2(w[(size_t)(kbase + 2) * FDIM + f],
                             w[(size_t)(kbase + 3) * FDIM + f]);
    unsigned d2 = pack_f16x2(w[(size_t)(kbase + 4) * FDIM + f],
                             w[(size_t)(kbase + 5) * FDIM + f]);
    unsigned d3 = pack_f16x2(w[(size_t)(kbase + 6) * FDIM + f],
                             w[(size_t)(kbase + 7) * FDIM + f]);
    *(uint4*)(g_wf + (idx >> 11) * 8192 + 4 * s) = make_uint4(d0, d1, d2, d3);
  }
}

// ---------------- fused GIN layer: 16 nodes/block, 8-wave cooperative -----
// Block = 512 thr (8 waves) = 16 nodes (625 blocks x 16 = 10000 exactly).
// Phase 1: wave w gathers nodes node0+2w, +1 with dwordx4 rows: lane
//   (quad q, m16) reads 16 B of row edge[4s+q] -> one wave-load consumes
//   4 edges (1 KB). Tails padded with sentinel zero row NNODES. Quad
//   partials folded by xor-16/xor-32 butterfly; quad-0 lanes write A row.
// Phase 2: wave w computes feature-tile n = wave with B-fragments held in
//   REGISTERS (4 dwordx4 from pre-packed L2-resident g_wf; no LDS W tile):
//   4 kchunks of v_mfma_f32_16x16x32_f16 (A/B frag [idx=lane&15][k=(lane>>4)*8+j];
//   D col=lane&15(+16n), row=(lane>>4)*4+reg).
// MODE 0: relu -> g_h1h (packed fp16x2). MODE 1: log_softmax -> out_g (fp32)
//         + re-zero this block's stripe counters.
// NOTE: no min-waves clause — allocator must keep the 8-deep gather batch
// (t[8] uint4 + 8 addrs) in registers; round-2 showed a 56-VGPR allocation
// serializes the batch and exposes full L2 latency per load.
template <int MODE>
__global__ __launch_bounds__(512) void gin_layer_kernel(
    const float* __restrict__ bvec,
    float* __restrict__ out_g) {
  const unsigned* __restrict__ xh = (MODE == 0) ? g_xh : g_h1h;

  __shared__ __align__(16) unsigned al[16 * 68];    // A tile (+4 pad/row), 4.35 KB
  __shared__ __align__(16) unsigned cfu[16 * 132];  // epilogue scratch, 8.45 KB

  const int tid = threadIdx.x;
  const int wave = tid >> 6, lane = tid & 63;
  const int quad = lane >> 4, m16 = lane & 15;
  const int node0 = blockIdx.x * 16;

  // ---- B-fragments straight to registers (L2-resident, pre-packed) ----
  uint4 bf[4];
  {
    const unsigned* wfp = g_wf + (MODE ? 8192 : 0);
#pragma unroll
    for (int kc = 0; kc < 4; ++kc)
      bf[kc] = *(const uint4*)(wfp + ((wave * 4 + kc) * 64 + lane) * 4);
  }
  const float bb = bvec[wave * 16 + m16];

  // ---- phase 1 prologue: self rows + stripe counters for my 2 nodes ----
  const int myn0 = node0 + wave * 2;
  uint4 self4[2];
  int o1[2], o2[2], o3[2], dgg[2];
#pragma unroll
  for (int i = 0; i < 2; ++i) {
    self4[i] = *(const uint4*)(xh + (size_t)(myn0 + i) * 64 + (m16 << 2));
    int4 c = *(const int4*)(g_cnt + (myn0 + i) * 4);
    int a = (c.x > SLOTS) ? SLOTS : c.x;
    int bq = (c.y > SLOTS) ? SLOTS : c.y;
    int cq = (c.z > SLOTS) ? SLOTS : c.z;
    int dq = (c.w > SLOTS) ? SLOTS : c.w;
    o1[i] = a; o2[i] = a + bq; o3[i] = a + bq + cq; dgg[i] = a + bq + cq + dq;
  }

  for (int i = 0; i < 2; ++i) {
    h2v a0 = as_h2(0u), a1 = as_h2(0u), a2 = as_h2(0u), a3 = as_h2(0u);
    const int deg = dgg[i];
    const int* nb = g_bucket + (size_t)(myn0 + i) * MAXDEG;
    for (int p = 0; p < deg; p += 64) {
      int n = deg - p; if (n > 64) n = 64;
      int myedge = NNODES;                 // sentinel zero row for padding
      if (lane < n) {                      // stripe-select index fetch
        int g = p + lane;
        int base = 0;
        if (g >= o1[i]) base = o1[i];
        if (g >= o2[i]) base = o2[i];
        if (g >= o3[i]) base = o3[i];
        int st = (g >= o1[i]) + (g >= o2[i]) + (g >= o3[i]);
        myedge = nb[st * SLOTS + (g - base)];
      }
      const int nst = (n + 3) >> 2;        // 4-edge steps (sentinel-padded)
      int s = 0;
      for (; s + 8 <= nst; s += 8) {       // 8 dwordx4 (=32 edges) in flight
        uint4 t[8];
#pragma unroll
        for (int k = 0; k < 8; ++k) {
          int e = __builtin_amdgcn_ds_bpermute((((s + k) << 2) | quad) << 2, myedge);
          t[k] = *(const uint4*)(xh + (unsigned)((e << 6) | (m16 << 2)));
        }
#pragma unroll
        for (int st2 = 1; st2 < 8; st2 <<= 1)
#pragma unroll
          for (int k = 0; k < 8; k += 2 * st2) vadd4(t[k], t[k + st2]);
        a0 += as_h2(t[0].x); a1 += as_h2(t[0].y);
        a2 += as_h2(t[0].z); a3 += as_h2(t[0].w);
      }
      if (s + 4 <= nst) {                  // 4-step batch (16 edges)
        uint4 t[4];
#pragma unroll
        for (int k = 0; k < 4; ++k) {
          int e = __builtin_amdgcn_ds_bpermute((((s + k) << 2) | quad) << 2, myedge);
          t[k] = *(const uint4*)(xh + (unsigned)((e << 6) | (m16 << 2)));
        }
        vadd4(t[0], t[1]); vadd4(t[2], t[3]); vadd4(t[0], t[2]);
        a0 += as_h2(t[0].x); a1 += as_h2(t[0].y);
        a2 += as_h2(t[0].z); a3 += as_h2(t[0].w);
        s += 4;
      }
      for (; s < nst; ++s) {               // <=3 single steps
        int e = __builtin_amdgcn_ds_bpermute(((s << 2) | quad) << 2, myedge);
        uint4 t = *(const uint4*)(xh + (unsigned)((e << 6) | (m16 << 2)));
        a0 += as_h2(t.x); a1 += as_h2(t.y); a2 += as_h2(t.z); a3 += as_h2(t.w);
      }
    }
    // fold the 4 quad partials (xor-16 then xor-32 butterfly)
    int r;
    r = __shfl_xor((int)as_u(a0), 16, 64); a0 += as_h2((unsigned)r);
    r = __shfl_xor((int)as_u(a0), 32, 64); a0 += as_h2((unsigned)r);
    r = __shfl_xor((int)as_u(a1), 16, 64); a1 += as_h2((unsigned)r);
    r = __shfl_xor((int)as_u(a1), 32, 64); a1 += as_h2((unsigned)r);
    r = __shfl_xor((int)as_u(a2), 16, 64); a2 += as_h2((unsigned)r);
    r = __shfl_xor((int)as_u(a2), 32, 64); a2 += as_h2((unsigned)r);
    r = __shfl_xor((int)as_u(a3), 16, 64); a3 += as_h2((unsigned)r);
    r = __shfl_xor((int)as_u(a3), 32, 64); a3 += as_h2((unsigned)r);
    // (1+eps)*x self term, added once after the fold
    a0 += as_h2(self4[i].x); a1 += as_h2(self4[i].y);
    a2 += as_h2(self4[i].z); a3 += as_h2(self4[i].w);
    if (quad == 0)
      *(uint4*)(al + (wave * 2 + i) * 68 + (m16 << 2)) =
          make_uint4(as_u(a0), as_u(a1), as_u(a2), as_u(a3));
  }
  __syncthreads();                         // A tile visible to all waves

  // ---- phase 2: MFMA, ntile n = wave, B from registers ----
  uint4 af[4];
#pragma unroll
  for (int kc = 0; kc < 4; ++kc)
    af[kc] = *(const uint4*)(al + m16 * 68 + kc * 16 + quad * 4);

  const int n = wave;
  f32x4 acc = {0.f, 0.f, 0.f, 0.f};
#pragma unroll
  for (int kc = 0; kc < 4; ++kc)
    acc = __builtin_amdgcn_mfma_f32_16x16x32_f16(
            __builtin_bit_cast(f16x8, af[kc]),
            __builtin_bit_cast(f16x8, bf[kc]), acc, 0, 0, 0);

  // ---- epilogue (cfu scratch, disjoint per wave until the sync) ----
  if (MODE == 0) {
    // relu + fp16 pack: rows padded to 136 halves for bank spread
    _Float16* ch = (_Float16*)cfu;
    const int f = n * 16 + m16;
#pragma unroll
    for (int reg = 0; reg < 4; ++reg)
      ch[(quad * 4 + reg) * 136 + f] = (_Float16)fmaxf(acc[reg] + bb, 0.f);
    __syncthreads();
    const int row = tid >> 5, c2 = (tid & 31) * 2;
    uint2 v = *(const uint2*)(cfu + row * 68 + c2);
    *(uint2*)(&g_h1h[(size_t)(node0 + row) * 64 + c2]) = v;
  } else {
    // log_softmax: vals to LDS fp32 (rows padded to 132 floats)
    float* cf = (float*)cfu;
    const int f = n * 16 + m16;
#pragma unroll
    for (int reg = 0; reg < 4; ++reg)
      cf[(quad * 4 + reg) * 132 + f] = acc[reg] + bb;
    __syncthreads();
    const int row = tid >> 5, li = tid & 31;   // 32 threads per row
    const float* base = cf + row * 132 + li * 4;
    float4 a4 = *(const float4*)(base);
    float mx = fmaxf(fmaxf(a4.x, a4.y), fmaxf(a4.z, a4.w));
#pragma unroll
    for (int off = 16; off >= 1; off >>= 1)
      mx = fmaxf(mx, __shfl_xor(mx, off, 64));   // within 32-lane half-wave
    float s = (__expf(a4.x - mx) + __expf(a4.y - mx))
            + (__expf(a4.z - mx) + __expf(a4.w - mx));
#pragma unroll
    for (int off = 16; off >= 1; off >>= 1)
      s += __shfl_xor(s, off, 64);
    const float ls = mx + __logf(s);
    float* orow = out_g + (size_t)(node0 + row) * FDIM + li * 4;
    *(float4*)(orow) = make_float4(a4.x - ls, a4.y - ls, a4.z - ls, a4.w - ls);
    // restore counter invariant: this block's 16 nodes x 4 stripes
    if (tid < 64) g_cnt[node0 * 4 + tid] = 0;
  }
}

extern "C" void kernel_launch(void* const* d_in, const int* in_sizes, int n_in,
                              void* d_out, int out_size, void* d_ws, size_t ws_size,
                              hipStream_t stream) {
  const float* x  = (const float*)d_in[0];
  const int*   ei = (const int*)d_in[1];     // int64 in reference -> int32 here
  const float* w1 = (const float*)d_in[2];
  const float* b1 = (const float*)d_in[3];
  const float* w2 = (const float*)d_in[4];
  const float* b2 = (const float*)d_in[5];
  float* out = (float*)d_out;

  const int E_ = in_sizes[1] / 2;
  const int EBLK = (E_ + 255) / 256;
  const int CBLK = (NNODES * 32 + 255) / 256;   // float4-granular cast
  const int WBLK = 16;                          // 4096 threads: 2x2048 W entries

  // ---- prep: bucket fill + cast + W pre-pack (counters zero by invariant) ----
  prep_kernel<<<EBLK + CBLK + WBLK, 256, 0, stream>>>(x, ei, w1, w2, E_, EBLK, CBLK);

  // ---- fused layers: 625 blocks x 8 waves x 2 nodes = 10000 exactly ----
  gin_layer_kernel<0><<<625, 512, 0, stream>>>(b1, nullptr);
  gin_layer_kernel<1><<<625, 512, 0, stream>>>(b2, out);
}

// Round 4
// 124.216 us; speedup vs baseline: 1.8429x; 1.0298x over previous
//
#include <hip/hip_runtime.h>
#include <cstdint>

#define NNODES 10000
#define FDIM 128
#define MAXDEG 192
#define SLOTS 48                           // per-stripe slots (4*48 = 192)

typedef _Float16 h2v  __attribute__((ext_vector_type(2)));
typedef _Float16 f16x8 __attribute__((ext_vector_type(8)));
typedef float    f32x4 __attribute__((ext_vector_type(4)));

// Module-owned scratch (BSS, zero at load) — no d_ws dependence.
// g_cnt invariant: zero at entry to every kernel_launch (BSS on first call;
// gin_layer<1> re-zeroes its blocks' counters after last use every call).
// Row NNODES of g_xh/g_h1h is a SENTINEL ZERO row (never written): gather
// batches are sentinel-padded to full 32-edge batches.
__device__ __align__(16)  int      g_cnt[NNODES * 4];     // striped degree counters
__device__                int      g_bucket[NNODES * MAXDEG]; // stripe sub-lists
__device__ __align__(256) unsigned g_xh [(NNODES + 1) * FDIM / 2]; // x  fp16x2
__device__ __align__(256) unsigned g_h1h[(NNODES + 1) * FDIM / 2]; // h1 fp16x2
__device__ __align__(16)  unsigned g_wf[2 * 8192];        // W1/W2 pre-packed B-frags

__device__ inline h2v as_h2(unsigned u) { return __builtin_bit_cast(h2v, u); }
__device__ inline unsigned as_u(h2v v) { return __builtin_bit_cast(unsigned, v); }
__device__ inline unsigned pack_f16x2(float a, float b) {
  h2v v; v[0] = (_Float16)a; v[1] = (_Float16)b;
  return as_u(v);
}
__device__ inline void vadd4(uint4& a, const uint4& b) {   // 4x v_pk_add_f16
  a.x = as_u(as_h2(a.x) + as_h2(b.x));
  a.y = as_u(as_h2(a.y) + as_h2(b.y));
  a.z = as_u(as_h2(a.z) + as_h2(b.z));
  a.w = as_u(as_h2(a.w) + as_h2(b.w));
}

// ---------------- prep: bucket fill + x cast (float4) + W pre-pack --------
__global__ __launch_bounds__(256) void prep_kernel(
    const float* __restrict__ x, const int* __restrict__ ei,
    const float* __restrict__ w1, const float* __restrict__ w2,
    int E_, int EBLK, int CBLK) {
  const int bid = blockIdx.x;
  if (bid < EBLK) {
    int e = bid * 256 + threadIdx.x;
    if (e < E_) {
      int d = ei[E_ + e];                  // dst
      int s = ei[e];                       // src
      int st = e & 3;
      int p = atomicAdd(&g_cnt[d * 4 + st], 1);
      if (p < SLOTS) g_bucket[d * MAXDEG + st * SLOTS + p] = s;
    }
  } else if (bid < EBLK + CBLK) {
    int i = (bid - EBLK) * 256 + threadIdx.x;
    if (i < NNODES * 32) {                 // float4 -> fp16x2 pair (16B->8B)
      float4 v = *(const float4*)(x + 4 * (size_t)i);
      uint2 o; o.x = pack_f16x2(v.x, v.y); o.y = pack_f16x2(v.z, v.w);
      *(uint2*)(g_xh + 2 * (size_t)i) = o;
    }
  } else {
    // pack W1/W2 into the exact MFMA B-fragment dword layout once.
    // entry s -> (nk = s>>6, sl = s&63), n = nk>>2, kc = nk&3,
    // kbase = kc*32 + (sl>>4)*8, f = n*16 + (sl&15).
    int idx = (bid - EBLK - CBLK) * 256 + threadIdx.x;  // 0..4095
    const float* w = (idx >= 2048) ? w2 : w1;
    int s = idx & 2047;
    int sl = s & 63, nk = s >> 6;
    int n = nk >> 2, kc = nk & 3;
    int kbase = kc * 32 + (sl >> 4) * 8;
    int f = n * 16 + (sl & 15);
    unsigned d0 = pack_f16x2(w[(size_t)(kbase + 0) * FDIM + f],
                             w[(size_t)(kbase + 1) * FDIM + f]);
    unsigned d1 = pack_f16x2(w[(size_t)(kbase + 2) * FDIM + f],
                             w[(size_t)(kbase + 3) * FDIM + f]);
    unsigned d2 = pack_f16x2(w[(size_t)(kbase + 4) * FDIM + f],
                             w[(size_t)(kbase + 5) * FDIM + f]);
    unsigned d3 = pack_f16x2(w[(size_t)(kbase + 6) * FDIM + f],
                             w[(size_t)(kbase + 7) * FDIM + f]);
    *(uint4*)(g_wf + (idx >> 11) * 8192 + 4 * s) = make_uint4(d0, d1, d2, d3);
  }
}

// ---------------- fused GIN layer: 8 nodes/block, 1 node/wave -------------
// Block = 512 thr (8 waves) = 8 nodes (1250 blocks x 8 = 10000 exactly).
// Gather: ALL bucket indices fetched up-front into 3 regs (deg<=192), then
//   uniform full 8-load batches (32 edges each, sentinel-padded): lane
//   (quad q, m16) reads 16 B of row edge[4s+q]. No mid-loop index fetches
//   -> consecutive batches have no memory dependence -> cross-batch MLP.
//   Quad partials folded by xor-16/xor-32 butterfly; quad-0 writes A row.
// MFMA: 16x16x32_f16, A rows 8..15 zeroed (outputs discarded); wave w owns
//   feature-tile n = w; B-fragments in registers from pre-packed g_wf.
// MODE 0: relu -> g_h1h (packed fp16x2). MODE 1: log_softmax -> out_g (fp32)
//         + re-zero this block's stripe counters.
// NOTE: no min-waves clause — round-2 showed a forced low-VGPR allocation
// serializes the load batches and exposes full L2 latency per load.
template <int MODE>
__global__ __launch_bounds__(512) void gin_layer_kernel(
    const float* __restrict__ bvec,
    float* __restrict__ out_g) {
  const unsigned* __restrict__ xh = (MODE == 0) ? g_xh : g_h1h;

  __shared__ __align__(16) unsigned al[16 * 68];   // A tile 16 x 64 dw (+4 pad)
  __shared__ __align__(16) unsigned cfu[8 * 132];  // epilogue scratch (8 rows)

  const int tid = threadIdx.x;
  const int wave = tid >> 6, lane = tid & 63;
  const int quad = lane >> 4, m16 = lane & 15;
  const int node0 = blockIdx.x * 8;
  const int myn = node0 + wave;            // this wave's node

  // ---- B-fragments straight to registers (L2-resident, pre-packed) ----
  uint4 bf[4];
  {
    const unsigned* wfp = g_wf + (MODE ? 8192 : 0);
#pragma unroll
    for (int kc = 0; kc < 4; ++kc)
      bf[kc] = *(const uint4*)(wfp + ((wave * 4 + kc) * 64 + lane) * 4);
  }
  const float bb = bvec[wave * 16 + m16];

  // zero A rows 8..15 (MFMA reads 16 rows; only 8 valid)
  for (int i2 = tid; i2 < 8 * 68; i2 += 512) al[8 * 68 + i2] = 0;

  // ---- prologue: self row + stripe counters ----
  uint4 self4 = *(const uint4*)(xh + (size_t)myn * 64 + (m16 << 2));
  int o1, o2, o3, deg;
  {
    int4 c = *(const int4*)(g_cnt + myn * 4);
    int a = (c.x > SLOTS) ? SLOTS : c.x;
    int bq = (c.y > SLOTS) ? SLOTS : c.y;
    int cq = (c.z > SLOTS) ? SLOTS : c.z;
    int dq = (c.w > SLOTS) ? SLOTS : c.w;
    o1 = a; o2 = a + bq; o3 = a + bq + cq; deg = a + bq + cq + dq;
  }

  // ---- fetch ALL edge indices up-front: 3 regs cover deg <= 192 ----
  const int* nb = g_bucket + (size_t)myn * MAXDEG;
  int idxr[3];
#pragma unroll
  for (int r = 0; r < 3; ++r) {
    int g = r * 64 + lane;
    int e = NNODES;                        // sentinel zero row
    if (g < deg) {
      int base = 0;
      if (g >= o1) base = o1;
      if (g >= o2) base = o2;
      if (g >= o3) base = o3;
      int st = (g >= o1) + (g >= o2) + (g >= o3);
      e = nb[st * SLOTS + (g - base)];
    }
    idxr[r] = e;
  }

  // ---- gather: uniform full batches of 8 dwordx4 loads (32 edges) ----
  h2v a0 = as_h2(0u), a1 = as_h2(0u), a2 = as_h2(0u), a3 = as_h2(0u);
  const int nbat = (deg + 31) >> 5;        // ceil(deg/32), <= 6
  for (int bt = 0; bt < nbat; ++bt) {
    const int s0 = bt << 3;                // first 4-edge step of this batch
    const int r = s0 >> 4;                 // index register for whole batch
    const int src = (r == 0) ? idxr[0] : ((r == 1) ? idxr[1] : idxr[2]);
    uint4 t[8];
#pragma unroll
    for (int k = 0; k < 8; ++k) {
      int e = __builtin_amdgcn_ds_bpermute(
          (((((s0 + k) & 15) << 2) | quad) << 2), src);
      t[k] = *(const uint4*)(xh + (unsigned)((e << 6) | (m16 << 2)));
    }
#pragma unroll
    for (int st2 = 1; st2 < 8; st2 <<= 1)
#pragma unroll
      for (int k = 0; k < 8; k += 2 * st2) vadd4(t[k], t[k + st2]);
    a0 += as_h2(t[0].x); a1 += as_h2(t[0].y);
    a2 += as_h2(t[0].z); a3 += as_h2(t[0].w);
  }

  // fold the 4 quad partials (xor-16 then xor-32 butterfly)
  int rr;
  rr = __shfl_xor((int)as_u(a0), 16, 64); a0 += as_h2((unsigned)rr);
  rr = __shfl_xor((int)as_u(a0), 32, 64); a0 += as_h2((unsigned)rr);
  rr = __shfl_xor((int)as_u(a1), 16, 64); a1 += as_h2((unsigned)rr);
  rr = __shfl_xor((int)as_u(a1), 32, 64); a1 += as_h2((unsigned)rr);
  rr = __shfl_xor((int)as_u(a2), 16, 64); a2 += as_h2((unsigned)rr);
  rr = __shfl_xor((int)as_u(a2), 32, 64); a2 += as_h2((unsigned)rr);
  rr = __shfl_xor((int)as_u(a3), 16, 64); a3 += as_h2((unsigned)rr);
  rr = __shfl_xor((int)as_u(a3), 32, 64); a3 += as_h2((unsigned)rr);
  // (1+eps)*x self term, added once after the fold
  a0 += as_h2(self4.x); a1 += as_h2(self4.y);
  a2 += as_h2(self4.z); a3 += as_h2(self4.w);
  if (quad == 0)
    *(uint4*)(al + wave * 68 + (m16 << 2)) =
        make_uint4(as_u(a0), as_u(a1), as_u(a2), as_u(a3));
  __syncthreads();                         // A tile visible to all waves

  // ---- MFMA: ntile n = wave, B from registers ----
  uint4 af[4];
#pragma unroll
  for (int kc = 0; kc < 4; ++kc)
    af[kc] = *(const uint4*)(al + m16 * 68 + kc * 16 + quad * 4);

  const int n = wave;
  f32x4 acc = {0.f, 0.f, 0.f, 0.f};
#pragma unroll
  for (int kc = 0; kc < 4; ++kc)
    acc = __builtin_amdgcn_mfma_f32_16x16x32_f16(
            __builtin_bit_cast(f16x8, af[kc]),
            __builtin_bit_cast(f16x8, bf[kc]), acc, 0, 0, 0);

  // ---- epilogue: D col=m16(+16n), row=quad*4+reg; rows 0..7 valid ----
  if (MODE == 0) {
    // relu + fp16 pack: rows padded to 136 halves for bank spread
    _Float16* ch = (_Float16*)cfu;
    const int f = n * 16 + m16;
    if (quad < 2) {
#pragma unroll
      for (int reg = 0; reg < 4; ++reg)
        ch[(quad * 4 + reg) * 136 + f] = (_Float16)fmaxf(acc[reg] + bb, 0.f);
    }
    __syncthreads();
    if (tid < 256) {
      const int row = tid >> 5, c2 = (tid & 31) * 2;
      uint2 v = *(const uint2*)(cfu + row * 68 + c2);
      *(uint2*)(&g_h1h[(size_t)(node0 + row) * 64 + c2]) = v;
    }
  } else {
    // log_softmax: vals to LDS fp32 (rows padded to 132 floats)
    float* cf = (float*)cfu;
    const int f = n * 16 + m16;
    if (quad < 2) {
#pragma unroll
      for (int reg = 0; reg < 4; ++reg)
        cf[(quad * 4 + reg) * 132 + f] = acc[reg] + bb;
    }
    __syncthreads();
    if (tid < 256) {
      const int row = tid >> 5, li = tid & 31;   // 32 threads per row
      const float* base = cf + row * 132 + li * 4;
      float4 a4 = *(const float4*)(base);
      float mx = fmaxf(fmaxf(a4.x, a4.y), fmaxf(a4.z, a4.w));
#pragma unroll
      for (int off = 16; off >= 1; off >>= 1)
        mx = fmaxf(mx, __shfl_xor(mx, off, 64));   // within 32-lane half-wave
      float s = (__expf(a4.x - mx) + __expf(a4.y - mx))
              + (__expf(a4.z - mx) + __expf(a4.w - mx));
#pragma unroll
      for (int off = 16; off >= 1; off >>= 1)
        s += __shfl_xor(s, off, 64);
      const float ls = mx + __logf(s);
      float* orow = out_g + (size_t)(node0 + row) * FDIM + li * 4;
      *(float4*)(orow) = make_float4(a4.x - ls, a4.y - ls, a4.z - ls, a4.w - ls);
    }
    // restore counter invariant: this block's 8 nodes x 4 stripes
    if (tid < 32) g_cnt[node0 * 4 + tid] = 0;
  }
}

extern "C" void kernel_launch(void* const* d_in, const int* in_sizes, int n_in,
                              void* d_out, int out_size, void* d_ws, size_t ws_size,
                              hipStream_t stream) {
  const float* x  = (const float*)d_in[0];
  const int*   ei = (const int*)d_in[1];     // int64 in reference -> int32 here
  const float* w1 = (const float*)d_in[2];
  const float* b1 = (const float*)d_in[3];
  const float* w2 = (const float*)d_in[4];
  const float* b2 = (const float*)d_in[5];
  float* out = (float*)d_out;

  const int E_ = in_sizes[1] / 2;
  const int EBLK = (E_ + 255) / 256;
  const int CBLK = (NNODES * 32 + 255) / 256;   // float4-granular cast
  const int WBLK = 16;                          // 4096 threads: 2x2048 W entries

  // ---- prep: bucket fill + cast + W pre-pack (counters zero by invariant) ----
  prep_kernel<<<EBLK + CBLK + WBLK, 256, 0, stream>>>(x, ei, w1, w2, E_, EBLK, CBLK);

  // ---- fused layers: 1250 blocks x 8 waves x 1 node = 10000 exactly ----
  gin_layer_kernel<0><<<1250, 512, 0, stream>>>(b1, nullptr);
  gin_layer_kernel<1><<<1250, 512, 0, stream>>>(b2, out);
}